// Round 5
// baseline (404.920 us; speedup 1.0000x reference)
//
#include <hip/hip_runtime.h>
#include <hip/hip_bf16.h>
#include <hip/hip_fp16.h>

#define N_NODES 50000
#define N_EDGES 800000
#define C_H 128
#define C_OUT 64
#define NBLK 196          // ceil(50000/256)
#define TSTRIDE 136       // LDS tile row stride in bf16
#define E_PAD 950272      // >= N_EDGES + 3*N_NODES, 1024-aligned
#define MM_BLKS 782       // ceil(50000/64) row-tiles for 16-row-tile matmuls
#define AGG_NG 391        // ceil(50000/128) node-groups per slice

typedef __attribute__((ext_vector_type(8))) short bf16x8;
typedef __attribute__((ext_vector_type(4))) float f32x4;

static __device__ __forceinline__ float bf_lo(unsigned int u) { return __uint_as_float(u << 16); }
static __device__ __forceinline__ float bf_hi(unsigned int u) { return __uint_as_float(u & 0xffff0000u); }
static __device__ __forceinline__ unsigned short f2bf(float f) {
    __hip_bfloat16 h = __float2bfloat16(f);
    return *(unsigned short*)&h;
}
static __device__ __forceinline__ unsigned int pack2(float a, float b) {
    return (unsigned int)f2bf(a) | ((unsigned int)f2bf(b) << 16);
}
static __device__ __forceinline__ unsigned short f2h_bits(float f) {
    union { __half h; unsigned short u; } c; c.h = __float2half_rn(f); return c.u;
}
static __device__ __forceinline__ float h_bits2f(unsigned short u) {
    union { __half h; unsigned short u; } c; c.u = u; return __half2float(c.h);
}

// ================= prep: hist(+rank) + pack W + zero epay =================
// block ranges: [0,3125) hist | [3125,3413) pack | [3413,4341) zero
__global__ void prep_kernel(const int* __restrict__ dst, int* __restrict__ counts,
                            int* __restrict__ rank,
                            const float* __restrict__ W1, const float* __restrict__ W2,
                            const float* __restrict__ W3, const float* __restrict__ Wd1,
                            const float* __restrict__ Wd2,
                            unsigned short* __restrict__ P1, unsigned short* __restrict__ P2,
                            unsigned short* __restrict__ P3, unsigned short* __restrict__ Pd1,
                            unsigned short* __restrict__ Pd2,
                            unsigned int* __restrict__ epay) {
    int b = blockIdx.x;
    if (b < 3125) {                               // hist over edges, capture rank
        int e = b * 256 + threadIdx.x;
        rank[e] = atomicAdd(&counts[dst[e]], 1);
    } else if (b < 3413) {                        // pack weights
        int idx = (b - 3125) * 256 + threadIdx.x;
        if (idx < 4 * 16384) {
            int which = idx >> 14;
            int r = idx & 16383;
            const float* W = (which == 0) ? W1 : (which == 1) ? W2 : (which == 2) ? W3 : Wd1;
            unsigned short* P = (which == 0) ? P1 : (which == 1) ? P2 : (which == 2) ? P3 : Pd1;
            int j = r & 7, lane = (r >> 3) & 63, t = r >> 9;
            int nb = t & 7, kb = t >> 3;          // NB=8
            int k = kb * 32 + ((lane >> 4) << 3) + j;
            int n = nb * 16 + (lane & 15);
            P[r] = f2bf(W[(size_t)k * 128 + n]);
        } else {
            int r = idx - 65536;
            if (r < 8192) {
                int j = r & 7, lane = (r >> 3) & 63, t = r >> 9;
                int nb = t & 3, kb = t >> 2;      // NB=4
                int k = kb * 32 + ((lane >> 4) << 3) + j;
                int n = nb * 16 + (lane & 15);
                Pd2[r] = f2bf(Wd2[(size_t)k * 64 + n]);
            }
        }
    } else {                                      // zero epay: 928 blocks x 1024 uints
        int i = (b - 3413) * 256 + threadIdx.x;
        *(uint4*)(epay + (size_t)i * 4) = make_uint4(0, 0, 0, 0);
    }
}

// ================= CSR scans (degree padded to multiple of 4) =================
__global__ void __launch_bounds__(256) scan1_kernel(const int* __restrict__ counts,
                                                    int* __restrict__ eblk,
                                                    int* __restrict__ bsum,
                                                    float* __restrict__ dinv) {
    __shared__ int ws[4];
    int i = blockIdx.x * 256 + threadIdx.x;
    int v = (i < N_NODES) ? counts[i] : 0;
    if (i < N_NODES) dinv[i] = rsqrtf((float)v + 1.0f);
    int vp = (v + 3) & ~3;                        // padded degree
    int lane = threadIdx.x & 63, w = threadIdx.x >> 6;
    int x = vp;
    #pragma unroll
    for (int off = 1; off < 64; off <<= 1) {
        int t = __shfl_up(x, off, 64);
        if (lane >= off) x += t;
    }
    if (lane == 63) ws[w] = x;
    __syncthreads();
    if (threadIdx.x == 0) {
        int run = 0;
        #pragma unroll
        for (int k = 0; k < 4; ++k) { int t = ws[k]; ws[k] = run; run += t; }
        bsum[blockIdx.x] = run;
    }
    __syncthreads();
    if (i < N_NODES) eblk[i] = x - vp + ws[w];
}

// merged scan2+scan3: every block redundantly scans the 196 block sums,
// picks its own exclusive offset, adds to per-element prefixes.
__global__ void __launch_bounds__(256) scanB_kernel(const int* __restrict__ eblk,
                                                    const int* __restrict__ bsum,
                                                    int* __restrict__ rowptr) {
    __shared__ int ws[4];
    __shared__ int sbo;
    int i = threadIdx.x;
    int v = (i < NBLK) ? bsum[i] : 0;
    int lane = i & 63, w = i >> 6;
    int x = v;
    #pragma unroll
    for (int off = 1; off < 64; off <<= 1) {
        int t = __shfl_up(x, off, 64);
        if (lane >= off) x += t;
    }
    if (lane == 63) ws[w] = x;
    __syncthreads();
    if (i == 0) {
        int run = 0;
        #pragma unroll
        for (int k = 0; k < 4; ++k) { int t = ws[k]; ws[k] = run; run += t; }
    }
    __syncthreads();
    int excl = x - v + ws[w];
    if (i == (int)blockIdx.x) sbo = excl;
    if (blockIdx.x == 0 && i == NBLK - 1) rowptr[N_NODES] = excl + v;
    __syncthreads();
    int g = blockIdx.x * 256 + threadIdx.x;
    if (g < N_NODES) rowptr[g] = eblk[g] + sbo;
}

// ================= heterogeneous: XW1 matmul + csr fill =================
__global__ void __launch_bounds__(256) fill_mm_kernel(
        const float* __restrict__ x, const unsigned short* __restrict__ P1,
        unsigned short* __restrict__ XW1,
        const int* __restrict__ src, const int* __restrict__ dst,
        const float* __restrict__ dinv,
        const int* __restrict__ rowptr, const int* __restrict__ rank,
        unsigned int* __restrict__ epay) {
    int b = blockIdx.x;
    if (b < MM_BLKS) {
        const int lane = threadIdx.x & 63;
        const int wave = threadIdx.x >> 6;
        const int wid  = b * 4 + wave;
        if (wid * 16 >= N_NODES) return;          // exact: 3125 waves used
        const int node = wid * 16 + (lane & 15);
        const int quad = lane >> 4;
        f32x4 acc[8];
        #pragma unroll
        for (int nb = 0; nb < 8; ++nb) acc[nb] = (f32x4){0.f, 0.f, 0.f, 0.f};
        #pragma unroll
        for (int kb = 0; kb < 4; ++kb) {
            const float* p = x + (size_t)node * 128 + kb * 32 + quad * 8;
            float4 lo = *(const float4*)p;
            float4 hi = *(const float4*)(p + 4);
            union { bf16x8 v; unsigned int u[4]; } tmp;
            tmp.u[0] = pack2(lo.x, lo.y); tmp.u[1] = pack2(lo.z, lo.w);
            tmp.u[2] = pack2(hi.x, hi.y); tmp.u[3] = pack2(hi.z, hi.w);
            #pragma unroll
            for (int nb = 0; nb < 8; ++nb) {
                bf16x8 wf = *(const bf16x8*)(P1 + ((size_t)(kb * 8 + nb) * 64 + lane) * 8);
                acc[nb] = __builtin_amdgcn_mfma_f32_16x16x32_bf16(wf, tmp.v, acc[nb], 0, 0, 0);
            }
        }
        #pragma unroll
        for (int nb = 0; nb < 8; ++nb) {
            int ch = nb * 16 + quad * 4;
            uint2 o;
            o.x = pack2(acc[nb][0], acc[nb][1]);
            o.y = pack2(acc[nb][2], acc[nb][3]);
            *(uint2*)(XW1 + (size_t)node * C_H + ch) = o;
        }
    } else {
        int e = (b - MM_BLKS) * 256 + threadIdx.x;
        if (e < N_EDGES) {
            int d = dst[e], s = src[e];
            int pos = rowptr[d] + rank[e];
            float nrm = dinv[s] * dinv[d];
            epay[pos] = (unsigned int)s | ((unsigned int)f2h_bits(nrm) << 16);
        }
    }
}

// ================= per-node aggregation inner loop (1 thread = 8 ch of 1 node) ====
struct Acc8 { float a0, a1, a2, a3, a4, a5, a6, a7; };

static __device__ __forceinline__ unsigned int ev_comp(const uint4 ea, const uint4 eb, int j) {
    switch (j) {
        case 0: return ea.x; case 1: return ea.y; case 2: return ea.z; case 3: return ea.w;
        case 4: return eb.x; case 5: return eb.y; case 6: return eb.z; default: return eb.w;
    }
}
static __device__ __forceinline__ unsigned int ev_comp4(const uint4 ev, int j) {
    switch (j) { case 0: return ev.x; case 1: return ev.y; case 2: return ev.z; default: return ev.w; }
}

#define ROW_FMA(rv, nm) \
    r.a0 = fmaf(bf_lo((rv).x), nm, r.a0); r.a1 = fmaf(bf_hi((rv).x), nm, r.a1); \
    r.a2 = fmaf(bf_lo((rv).y), nm, r.a2); r.a3 = fmaf(bf_hi((rv).y), nm, r.a3); \
    r.a4 = fmaf(bf_lo((rv).z), nm, r.a4); r.a5 = fmaf(bf_hi((rv).z), nm, r.a5); \
    r.a6 = fmaf(bf_lo((rv).w), nm, r.a6); r.a7 = fmaf(bf_hi((rv).w), nm, r.a7);

static __device__ __forceinline__ Acc8 agg_row(
        const int* __restrict__ rowptr,
        const unsigned int* __restrict__ epay,
        const unsigned short* __restrict__ hin,
        const float* __restrict__ dinv,
        int node, int c8) {
    const unsigned short* hc = hin + c8;
    float di = dinv[node], dii = di * di;
    uint4 raw = *(const uint4*)(hc + (size_t)node * C_H);
    Acc8 r;
    r.a0 = bf_lo(raw.x) * dii; r.a1 = bf_hi(raw.x) * dii;
    r.a2 = bf_lo(raw.y) * dii; r.a3 = bf_hi(raw.y) * dii;
    r.a4 = bf_lo(raw.z) * dii; r.a5 = bf_hi(raw.z) * dii;
    r.a6 = bf_lo(raw.w) * dii; r.a7 = bf_hi(raw.w) * dii;

    int beg = rowptr[node], end = rowptr[node + 1];
    int deg = end - beg;                 // multiple of 4
    int n8 = deg >> 3;                   // full 8-edge chunks
    int tail = (deg >> 2) & 1;           // one trailing 4-edge chunk?
    const unsigned int* ep = epay + beg;

    for (int k = 0; k < n8; ++k) {
        uint4 ea = *(const uint4*)(ep + (k << 3));
        uint4 eb = *(const uint4*)(ep + (k << 3) + 4);
        uint4 rv[8];
        #pragma unroll
        for (int j = 0; j < 8; ++j)
            rv[j] = *(const uint4*)(hc + (size_t)(ev_comp(ea, eb, j) & 0xffffu) * C_H);
        #pragma unroll
        for (int j = 0; j < 8; ++j) {
            float nm = h_bits2f((unsigned short)(ev_comp(ea, eb, j) >> 16));
            ROW_FMA(rv[j], nm);
        }
    }
    if (tail) {
        uint4 ev = *(const uint4*)(ep + (n8 << 3));
        uint4 rv[4];
        #pragma unroll
        for (int j = 0; j < 4; ++j)
            rv[j] = *(const uint4*)(hc + (size_t)(ev_comp4(ev, j) & 0xffffu) * C_H);
        #pragma unroll
        for (int j = 0; j < 4; ++j) {
            float nm = h_bits2f((unsigned short)(ev_comp4(ev, j) >> 16));
            ROW_FMA(rv[j], nm);
        }
    }
    return r;
}

// ================= XCD-sliced aggregation =================
// slice = blockIdx & 7 (native dispatch round-robins wgs across the 8 XCDs, so
// all blocks of slice s land on XCD s). Slice s touches only channels
// [16s, 16s+16) of hin: 50000 x 32 B = 1.6 MB -> resident in that XCD's 4 MB L2.
// 2 threads/node x 8 slices = 16 chains/node (same as the fused baseline).
template <bool BIASRELU>
__global__ void __launch_bounds__(256) agg_kernel(
        const int* __restrict__ rowptr,
        const unsigned int* __restrict__ epay,
        const float* __restrict__ dinv,
        const unsigned short* __restrict__ hin,
        const float* __restrict__ bias,
        unsigned short* __restrict__ out) {
    const int t = threadIdx.x;
    const unsigned int b = blockIdx.x;
    const int slice = (int)(b & 7u);
    const int node  = (int)(b >> 3) * 128 + (t >> 1);
    if (node >= N_NODES) return;
    const int c8 = slice * 16 + (t & 1) * 8;

    Acc8 r = agg_row(rowptr, epay, hin, dinv, node, c8);

    float a0, a1, a2, a3, a4, a5, a6, a7;
    if (BIASRELU) {
        float4 ba = *(const float4*)(bias + c8);
        float4 bb = *(const float4*)(bias + c8 + 4);
        a0 = fmaxf(r.a0 + ba.x, 0.f); a1 = fmaxf(r.a1 + ba.y, 0.f);
        a2 = fmaxf(r.a2 + ba.z, 0.f); a3 = fmaxf(r.a3 + ba.w, 0.f);
        a4 = fmaxf(r.a4 + bb.x, 0.f); a5 = fmaxf(r.a5 + bb.y, 0.f);
        a6 = fmaxf(r.a6 + bb.z, 0.f); a7 = fmaxf(r.a7 + bb.w, 0.f);
    } else {
        a0 = r.a0; a1 = r.a1; a2 = r.a2; a3 = r.a3;
        a4 = r.a4; a5 = r.a5; a6 = r.a6; a7 = r.a7;
    }
    uint4 o;
    o.x = pack2(a0, a1); o.y = pack2(a2, a3);
    o.z = pack2(a4, a5); o.w = pack2(a6, a7);
    *(uint4*)(out + (size_t)node * C_H + c8) = o;
}

// ================= dense mm: out = relu(hin @ Wp + bias) -> bf16 =================
__global__ void __launch_bounds__(256) mmbr_kernel(
        const unsigned short* __restrict__ hin,
        const unsigned short* __restrict__ Wp,
        const float* __restrict__ bias,
        unsigned short* __restrict__ out) {
    const int lane = threadIdx.x & 63;
    const int wave = threadIdx.x >> 6;
    const int wid  = blockIdx.x * 4 + wave;
    if (wid * 16 >= N_NODES) return;              // exact: 3125 waves used
    const int node = wid * 16 + (lane & 15);
    const int quad = lane >> 4;
    f32x4 acc[8];
    #pragma unroll
    for (int nb = 0; nb < 8; ++nb) acc[nb] = (f32x4){0.f, 0.f, 0.f, 0.f};
    #pragma unroll
    for (int kb = 0; kb < 4; ++kb) {
        bf16x8 hf = *(const bf16x8*)(hin + (size_t)node * C_H + kb * 32 + quad * 8);
        #pragma unroll
        for (int nb = 0; nb < 8; ++nb) {
            bf16x8 wf = *(const bf16x8*)(Wp + ((size_t)(kb * 8 + nb) * 64 + lane) * 8);
            acc[nb] = __builtin_amdgcn_mfma_f32_16x16x32_bf16(wf, hf, acc[nb], 0, 0, 0);
        }
    }
    #pragma unroll
    for (int nb = 0; nb < 8; ++nb) {
        int ch = nb * 16 + quad * 4;
        float4 bb = *(const float4*)(bias + ch);
        uint2 o;
        o.x = pack2(fmaxf(acc[nb][0] + bb.x, 0.f), fmaxf(acc[nb][1] + bb.y, 0.f));
        o.y = pack2(fmaxf(acc[nb][2] + bb.z, 0.f), fmaxf(acc[nb][3] + bb.w, 0.f));
        *(uint2*)(out + (size_t)node * C_H + ch) = o;
    }
}

// ======== final: relu(G3@W3+b3) -> relu(@Wd1+bd1) -> @Wd2+bd2 -> sigmoid ========
__global__ void __launch_bounds__(256) final_kernel(
        const unsigned short* __restrict__ g3,
        const unsigned short* __restrict__ P3p, const float* __restrict__ b3,
        const unsigned short* __restrict__ Wd1p, const float* __restrict__ bd1,
        const unsigned short* __restrict__ Wd2p, const float* __restrict__ bd2,
        float* __restrict__ out_f) {
    __shared__ unsigned short sG[16 * TSTRIDE];
    const int t = threadIdx.x;
    {
        int nl = t >> 4, c8 = (t & 15) << 3;
        int node = blockIdx.x * 16 + nl;
        *(uint4*)(sG + nl * TSTRIDE + c8) = *(const uint4*)(g3 + (size_t)node * C_H + c8);
    }
    __syncthreads();

    const int lane = t & 63, wave = t >> 6, quad = lane >> 4, row = lane & 15;
    const int node = blockIdx.x * 16 + row;
    const int nb0 = 2 * wave, nb1 = 2 * wave + 1;

    // stage 1: @P3 + b3, relu
    f32x4 acc0 = (f32x4){0.f, 0.f, 0.f, 0.f};
    f32x4 acc1 = (f32x4){0.f, 0.f, 0.f, 0.f};
    #pragma unroll
    for (int kb = 0; kb < 4; ++kb) {
        bf16x8 hf = *(const bf16x8*)(sG + row * TSTRIDE + kb * 32 + quad * 8);
        bf16x8 wf0 = *(const bf16x8*)(P3p + ((size_t)(kb * 8 + nb0) * 64 + lane) * 8);
        bf16x8 wf1 = *(const bf16x8*)(P3p + ((size_t)(kb * 8 + nb1) * 64 + lane) * 8);
        acc0 = __builtin_amdgcn_mfma_f32_16x16x32_bf16(wf0, hf, acc0, 0, 0, 0);
        acc1 = __builtin_amdgcn_mfma_f32_16x16x32_bf16(wf1, hf, acc1, 0, 0, 0);
    }
    float4 ba0 = *(const float4*)(b3 + nb0 * 16 + quad * 4);
    float4 ba1 = *(const float4*)(b3 + nb1 * 16 + quad * 4);
    float v00 = fmaxf(acc0[0] + ba0.x, 0.f), v01 = fmaxf(acc0[1] + ba0.y, 0.f);
    float v02 = fmaxf(acc0[2] + ba0.z, 0.f), v03 = fmaxf(acc0[3] + ba0.w, 0.f);
    float v10 = fmaxf(acc1[0] + ba1.x, 0.f), v11 = fmaxf(acc1[1] + ba1.y, 0.f);
    float v12 = fmaxf(acc1[2] + ba1.z, 0.f), v13 = fmaxf(acc1[3] + ba1.w, 0.f);
    __syncthreads();
    {
        uint2 o0, o1;
        o0.x = pack2(v00, v01); o0.y = pack2(v02, v03);
        o1.x = pack2(v10, v11); o1.y = pack2(v12, v13);
        *(uint2*)(sG + row * TSTRIDE + nb0 * 16 + quad * 4) = o0;
        *(uint2*)(sG + row * TSTRIDE + nb1 * 16 + quad * 4) = o1;
    }
    __syncthreads();

    // stage 2: @Wd1 + bd1, relu
    acc0 = (f32x4){0.f, 0.f, 0.f, 0.f};
    acc1 = (f32x4){0.f, 0.f, 0.f, 0.f};
    #pragma unroll
    for (int kb = 0; kb < 4; ++kb) {
        bf16x8 hf = *(const bf16x8*)(sG + row * TSTRIDE + kb * 32 + quad * 8);
        bf16x8 wf0 = *(const bf16x8*)(Wd1p + ((size_t)(kb * 8 + nb0) * 64 + lane) * 8);
        bf16x8 wf1 = *(const bf16x8*)(Wd1p + ((size_t)(kb * 8 + nb1) * 64 + lane) * 8);
        acc0 = __builtin_amdgcn_mfma_f32_16x16x32_bf16(wf0, hf, acc0, 0, 0, 0);
        acc1 = __builtin_amdgcn_mfma_f32_16x16x32_bf16(wf1, hf, acc1, 0, 0, 0);
    }
    ba0 = *(const float4*)(bd1 + nb0 * 16 + quad * 4);
    ba1 = *(const float4*)(bd1 + nb1 * 16 + quad * 4);
    v00 = fmaxf(acc0[0] + ba0.x, 0.f); v01 = fmaxf(acc0[1] + ba0.y, 0.f);
    v02 = fmaxf(acc0[2] + ba0.z, 0.f); v03 = fmaxf(acc0[3] + ba0.w, 0.f);
    v10 = fmaxf(acc1[0] + ba1.x, 0.f); v11 = fmaxf(acc1[1] + ba1.y, 0.f);
    v12 = fmaxf(acc1[2] + ba1.z, 0.f); v13 = fmaxf(acc1[3] + ba1.w, 0.f);
    __syncthreads();
    {
        uint2 o0, o1;
        o0.x = pack2(v00, v01); o0.y = pack2(v02, v03);
        o1.x = pack2(v10, v11); o1.y = pack2(v12, v13);
        *(uint2*)(sG + row * TSTRIDE + nb0 * 16 + quad * 4) = o0;
        *(uint2*)(sG + row * TSTRIDE + nb1 * 16 + quad * 4) = o1;
    }
    __syncthreads();

    // stage 3: @Wd2 + bd2 -> sigmoid
    f32x4 acc = (f32x4){0.f, 0.f, 0.f, 0.f};
    #pragma unroll
    for (int kb = 0; kb < 4; ++kb) {
        bf16x8 hf = *(const bf16x8*)(sG + row * TSTRIDE + kb * 32 + quad * 8);
        bf16x8 wf = *(const bf16x8*)(Wd2p + ((size_t)(kb * 4 + wave) * 64 + lane) * 8);
        acc = __builtin_amdgcn_mfma_f32_16x16x32_bf16(wf, hf, acc, 0, 0, 0);
    }
    int ch = wave * 16 + quad * 4;
    float4 b4 = *(const float4*)(bd2 + ch);
    float4 rr;
    rr.x = 1.f / (1.f + expf(-(acc[0] + b4.x)));
    rr.y = 1.f / (1.f + expf(-(acc[1] + b4.y)));
    rr.z = 1.f / (1.f + expf(-(acc[2] + b4.z)));
    rr.w = 1.f / (1.f + expf(-(acc[3] + b4.w)));
    *(float4*)(out_f + (size_t)node * C_OUT + ch) = rr;
}

extern "C" void kernel_launch(void* const* d_in, const int* in_sizes, int n_in,
                              void* d_out, int out_size, void* d_ws, size_t ws_size,
                              hipStream_t stream) {
    const float* x   = (const float*)d_in[0];
    const int*   ei  = (const int*)d_in[1];
    const float* W1  = (const float*)d_in[2];
    const float* b1  = (const float*)d_in[3];
    const float* W2  = (const float*)d_in[4];
    const float* b2  = (const float*)d_in[5];
    const float* W3  = (const float*)d_in[6];
    const float* b3  = (const float*)d_in[7];
    const float* Wd1 = (const float*)d_in[8];
    const float* bd1 = (const float*)d_in[9];
    const float* Wd2 = (const float*)d_in[10];
    const float* bd2 = (const float*)d_in[11];

    const int* src = ei;
    const int* dst = ei + N_EDGES;

    char* base = (char*)d_ws;
    size_t off = 0;
    auto alloc = [&](size_t bytes) { char* p = base + off; off += (bytes + 255) & ~size_t(255); return p; };
    int*            counts = (int*)alloc(50176 * 4);
    unsigned int*   epay   = (unsigned int*)alloc((size_t)E_PAD * 4);
    int*            rank   = (int*)alloc((size_t)N_EDGES * 4);
    float*          dinv   = (float*)alloc(N_NODES * 4);
    int*            rowptr = (int*)alloc((N_NODES + 1) * 4);
    int*            eblk   = (int*)alloc(N_NODES * 4);
    int*            bsum   = (int*)alloc(256 * 4);
    unsigned short* XW1    = (unsigned short*)alloc((size_t)N_NODES * C_H * 2);
    unsigned short* bufA   = (unsigned short*)alloc((size_t)N_NODES * C_H * 2);
    unsigned short* bufB   = (unsigned short*)alloc((size_t)N_NODES * C_H * 2);
    unsigned short* P1     = (unsigned short*)alloc(128 * 128 * 2);
    unsigned short* P2     = (unsigned short*)alloc(128 * 128 * 2);
    unsigned short* P3     = (unsigned short*)alloc(128 * 128 * 2);
    unsigned short* Pd1    = (unsigned short*)alloc(128 * 128 * 2);
    unsigned short* Pd2    = (unsigned short*)alloc(128 * 64 * 2);

    const int T = 256;
    dim3 blk(T);
    dim3 gN((N_NODES + T - 1) / T);            // 196
    dim3 gPrep(3125 + 288 + 928);              // hist + pack + zero
    dim3 gFillMM(MM_BLKS + 3125);              // mm + fill
    dim3 gAgg(AGG_NG * 8);                     // 3128: slice = blockIdx & 7
    dim3 gMM(MM_BLKS);                         // 782
    dim3 gFinal(N_NODES / 16);                 // 3125, exact

    hipMemsetAsync(counts, 0, 50176 * 4, stream);
    prep_kernel<<<gPrep, blk, 0, stream>>>(dst, counts, rank,
                                           W1, W2, W3, Wd1, Wd2,
                                           P1, P2, P3, Pd1, Pd2, epay);
    scan1_kernel<<<gN, blk, 0, stream>>>(counts, eblk, bsum, dinv);
    scanB_kernel<<<gN, blk, 0, stream>>>(eblk, bsum, rowptr);
    fill_mm_kernel<<<gFillMM, blk, 0, stream>>>(x, P1, XW1, src, dst, dinv,
                                                rowptr, rank, epay);

    // layer 1: A1 = relu(agg(x@W1) + b1)            XW1 -> bufA
    agg_kernel<true><<<gAgg, blk, 0, stream>>>(rowptr, epay, dinv, XW1, b1, bufA);
    // layer 2: G2 = agg(A1)                         bufA -> bufB
    agg_kernel<false><<<gAgg, blk, 0, stream>>>(rowptr, epay, dinv, bufA, nullptr, bufB);
    //          A2 = relu(G2@W2 + b2)                bufB -> XW1
    mmbr_kernel<<<gMM, blk, 0, stream>>>(bufB, P2, b2, XW1);
    // layer 3: G3 = agg(A2)                         XW1 -> bufB
    agg_kernel<false><<<gAgg, blk, 0, stream>>>(rowptr, epay, dinv, XW1, nullptr, bufB);
    // head: relu(G3@W3+b3) -> relu(@Wd1+bd1) -> @Wd2+bd2 -> sigmoid
    final_kernel<<<gFinal, blk, 0, stream>>>(bufB, P3, b3, Pd1, bd1, Pd2, bd2,
                                             (float*)d_out);
}

// Round 6
// 251.109 us; speedup vs baseline: 1.6125x; 1.6125x over previous
//
#include <hip/hip_runtime.h>
#include <hip/hip_bf16.h>
#include <hip/hip_fp16.h>

#define N_NODES 50000
#define N_EDGES 800000
#define C_H 128
#define C_OUT 64
#define NBLK 196          // ceil(50000/256)
#define TSTRIDE 136       // LDS tile row stride in bf16
#define E_PAD 950272      // >= N_EDGES + 3*N_NODES, 1024-aligned
#define MM_BLKS 782       // ceil(50000/64) row-tiles for the XW1 matmul
#define TILE_N 6250       // src-tile width (8 tiles): 6250 rows x 256 B = 1.6 MB, L2-line-resident

typedef __attribute__((ext_vector_type(8))) short bf16x8;
typedef __attribute__((ext_vector_type(4))) float f32x4;

static __device__ __forceinline__ float bf_lo(unsigned int u) { return __uint_as_float(u << 16); }
static __device__ __forceinline__ float bf_hi(unsigned int u) { return __uint_as_float(u & 0xffff0000u); }
static __device__ __forceinline__ unsigned short f2bf(float f) {
    __hip_bfloat16 h = __float2bfloat16(f);
    return *(unsigned short*)&h;
}
static __device__ __forceinline__ unsigned int pack2(float a, float b) {
    return (unsigned int)f2bf(a) | ((unsigned int)f2bf(b) << 16);
}
static __device__ __forceinline__ unsigned short f2h_bits(float f) {
    union { __half h; unsigned short u; } c; c.h = __float2half_rn(f); return c.u;
}
static __device__ __forceinline__ float h_bits2f(unsigned short u) {
    union { __half h; unsigned short u; } c; c.u = u; return __half2float(c.h);
}

// ================= prep: (dst,src-tile) hist(+rank) + pack W + zero epay ==========
// block ranges: [0,3125) hist | [3125,3413) pack | [3413,4341) zero
__global__ void prep_kernel(const int* __restrict__ src, const int* __restrict__ dst,
                            int* __restrict__ counts2,
                            int* __restrict__ rank,
                            const float* __restrict__ W1, const float* __restrict__ W2,
                            const float* __restrict__ W3, const float* __restrict__ Wd1,
                            const float* __restrict__ Wd2,
                            unsigned short* __restrict__ P1, unsigned short* __restrict__ P2,
                            unsigned short* __restrict__ P3, unsigned short* __restrict__ Pd1,
                            unsigned short* __restrict__ Pd2,
                            unsigned int* __restrict__ epay) {
    int b = blockIdx.x;
    if (b < 3125) {                               // hist over (dst, src-tile), capture rank
        int e = b * 256 + threadIdx.x;
        int d = dst[e], s = src[e];
        int t = s / TILE_N;                       // 0..7
        rank[e] = atomicAdd(&counts2[d * 8 + t], 1);
    } else if (b < 3413) {                        // pack weights
        int idx = (b - 3125) * 256 + threadIdx.x;
        if (idx < 4 * 16384) {
            int which = idx >> 14;
            int r = idx & 16383;
            const float* W = (which == 0) ? W1 : (which == 1) ? W2 : (which == 2) ? W3 : Wd1;
            unsigned short* P = (which == 0) ? P1 : (which == 1) ? P2 : (which == 2) ? P3 : Pd1;
            int j = r & 7, lane = (r >> 3) & 63, t = r >> 9;
            int nb = t & 7, kb = t >> 3;          // NB=8
            int k = kb * 32 + ((lane >> 4) << 3) + j;
            int n = nb * 16 + (lane & 15);
            P[r] = f2bf(W[(size_t)k * 128 + n]);
        } else {
            int r = idx - 65536;
            if (r < 8192) {
                int j = r & 7, lane = (r >> 3) & 63, t = r >> 9;
                int nb = t & 3, kb = t >> 2;      // NB=4
                int k = kb * 32 + ((lane >> 4) << 3) + j;
                int n = nb * 16 + (lane & 15);
                Pd2[r] = f2bf(Wd2[(size_t)k * 64 + n]);
            }
        }
    } else {                                      // zero epay: 928 blocks x 1024 uints
        int i = (b - 3413) * 256 + threadIdx.x;
        *(uint4*)(epay + (size_t)i * 4) = make_uint4(0, 0, 0, 0);
    }
}

// ================= CSR scans (row degree padded to multiple of 4) =================
// scan1: per-row 8-wide exclusive bucket scan (in place in counts2), degree = sum;
// then the usual block-level padded-degree prefix.
__global__ void __launch_bounds__(256) scan1_kernel(int* __restrict__ counts2,
                                                    int* __restrict__ eblk,
                                                    int* __restrict__ bsum,
                                                    float* __restrict__ dinv) {
    __shared__ int ws[4];
    int i = blockIdx.x * 256 + threadIdx.x;
    int deg = 0;
    if (i < N_NODES) {
        int* c = counts2 + (size_t)i * 8;
        uint4 a = *(uint4*)c;
        uint4 bq = *(uint4*)(c + 4);
        int run = 0, tv;
        tv = a.x;  a.x  = run; run += tv;
        tv = a.y;  a.y  = run; run += tv;
        tv = a.z;  a.z  = run; run += tv;
        tv = a.w;  a.w  = run; run += tv;
        tv = bq.x; bq.x = run; run += tv;
        tv = bq.y; bq.y = run; run += tv;
        tv = bq.z; bq.z = run; run += tv;
        tv = bq.w; bq.w = run; run += tv;
        deg = run;
        *(uint4*)c = a;
        *(uint4*)(c + 4) = bq;
        dinv[i] = rsqrtf((float)deg + 1.0f);
    }
    int vp = (deg + 3) & ~3;                      // padded degree
    int lane = threadIdx.x & 63, w = threadIdx.x >> 6;
    int x = vp;
    #pragma unroll
    for (int off = 1; off < 64; off <<= 1) {
        int t = __shfl_up(x, off, 64);
        if (lane >= off) x += t;
    }
    if (lane == 63) ws[w] = x;
    __syncthreads();
    if (threadIdx.x == 0) {
        int run = 0;
        #pragma unroll
        for (int k = 0; k < 4; ++k) { int t = ws[k]; ws[k] = run; run += t; }
        bsum[blockIdx.x] = run;
    }
    __syncthreads();
    if (i < N_NODES) eblk[i] = x - vp + ws[w];
}

// merged scan2+scan3: every block redundantly scans the 196 block sums,
// picks its own exclusive offset, adds to per-element prefixes.
__global__ void __launch_bounds__(256) scanB_kernel(const int* __restrict__ eblk,
                                                    const int* __restrict__ bsum,
                                                    int* __restrict__ rowptr) {
    __shared__ int ws[4];
    __shared__ int sbo;
    int i = threadIdx.x;
    int v = (i < NBLK) ? bsum[i] : 0;
    int lane = i & 63, w = i >> 6;
    int x = v;
    #pragma unroll
    for (int off = 1; off < 64; off <<= 1) {
        int t = __shfl_up(x, off, 64);
        if (lane >= off) x += t;
    }
    if (lane == 63) ws[w] = x;
    __syncthreads();
    if (i == 0) {
        int run = 0;
        #pragma unroll
        for (int k = 0; k < 4; ++k) { int t = ws[k]; ws[k] = run; run += t; }
    }
    __syncthreads();
    int excl = x - v + ws[w];
    if (i == (int)blockIdx.x) sbo = excl;
    if (blockIdx.x == 0 && i == NBLK - 1) rowptr[N_NODES] = excl + v;
    __syncthreads();
    int g = blockIdx.x * 256 + threadIdx.x;
    if (g < N_NODES) rowptr[g] = eblk[g] + sbo;
}

// ================= heterogeneous: XW1 matmul + csr fill (tile-ordered) ============
__global__ void __launch_bounds__(256) fill_mm_kernel(
        const float* __restrict__ x, const unsigned short* __restrict__ P1,
        unsigned short* __restrict__ XW1,
        const int* __restrict__ src, const int* __restrict__ dst,
        const float* __restrict__ dinv,
        const int* __restrict__ rowptr, const int* __restrict__ counts2,
        const int* __restrict__ rank,
        unsigned int* __restrict__ epay) {
    int b = blockIdx.x;
    if (b < MM_BLKS) {
        const int lane = threadIdx.x & 63;
        const int wave = threadIdx.x >> 6;
        const int wid  = b * 4 + wave;
        if (wid * 16 >= N_NODES) return;          // exact: 3125 waves used
        const int node = wid * 16 + (lane & 15);
        const int quad = lane >> 4;
        f32x4 acc[8];
        #pragma unroll
        for (int nb = 0; nb < 8; ++nb) acc[nb] = (f32x4){0.f, 0.f, 0.f, 0.f};
        #pragma unroll
        for (int kb = 0; kb < 4; ++kb) {
            const float* p = x + (size_t)node * 128 + kb * 32 + quad * 8;
            float4 lo = *(const float4*)p;
            float4 hi = *(const float4*)(p + 4);
            union { bf16x8 v; unsigned int u[4]; } tmp;
            tmp.u[0] = pack2(lo.x, lo.y); tmp.u[1] = pack2(lo.z, lo.w);
            tmp.u[2] = pack2(hi.x, hi.y); tmp.u[3] = pack2(hi.z, hi.w);
            #pragma unroll
            for (int nb = 0; nb < 8; ++nb) {
                bf16x8 wf = *(const bf16x8*)(P1 + ((size_t)(kb * 8 + nb) * 64 + lane) * 8);
                acc[nb] = __builtin_amdgcn_mfma_f32_16x16x32_bf16(wf, tmp.v, acc[nb], 0, 0, 0);
            }
        }
        #pragma unroll
        for (int nb = 0; nb < 8; ++nb) {
            int ch = nb * 16 + quad * 4;
            uint2 o;
            o.x = pack2(acc[nb][0], acc[nb][1]);
            o.y = pack2(acc[nb][2], acc[nb][3]);
            *(uint2*)(XW1 + (size_t)node * C_H + ch) = o;
        }
    } else {
        int e = (b - MM_BLKS) * 256 + threadIdx.x;
        if (e < N_EDGES) {
            int d = dst[e], s = src[e];
            int t = s / TILE_N;
            int pos = rowptr[d] + counts2[d * 8 + t] + rank[e];
            float nrm = dinv[s] * dinv[d];
            epay[pos] = (unsigned int)s | ((unsigned int)f2h_bits(nrm) << 16);
        }
    }
}

// ================= layer 1: pure gather(XW1) + bias + relu -> bf16 =================
__global__ void __launch_bounds__(256) gather1_kernel(
        const int* __restrict__ rowptr,
        const unsigned int* __restrict__ epay,
        const float* __restrict__ dinv,
        const unsigned short* __restrict__ hin,
        const float* __restrict__ bias,
        unsigned short* __restrict__ out) {
    int t    = blockIdx.x * 256 + threadIdx.x;
    int node = t >> 4;
    int c8   = (t & 15) << 3;

    float di = dinv[node], dii = di * di;
    uint4 raw = *(const uint4*)(hin + (size_t)node * C_H + c8);
    float a0 = bf_lo(raw.x) * dii, a1 = bf_hi(raw.x) * dii;
    float a2 = bf_lo(raw.y) * dii, a3 = bf_hi(raw.y) * dii;
    float a4 = bf_lo(raw.z) * dii, a5 = bf_hi(raw.z) * dii;
    float a6 = bf_lo(raw.w) * dii, a7 = bf_hi(raw.w) * dii;
    int beg = rowptr[node], end = rowptr[node + 1];
    int p = beg;
    for (; p + 8 <= end; p += 8) {
        uint4 ev0 = *(const uint4*)(epay + p);
        uint4 ev1 = *(const uint4*)(epay + p + 4);
        unsigned int ee[8] = {ev0.x, ev0.y, ev0.z, ev0.w, ev1.x, ev1.y, ev1.z, ev1.w};
        uint4 rv[8];
        #pragma unroll
        for (int j = 0; j < 8; ++j)
            rv[j] = *(const uint4*)(hin + (size_t)(ee[j] & 0xffffu) * C_H + c8);
        #pragma unroll
        for (int j = 0; j < 8; ++j) {
            float nm = h_bits2f((unsigned short)(ee[j] >> 16));
            a0 = fmaf(bf_lo(rv[j].x), nm, a0); a1 = fmaf(bf_hi(rv[j].x), nm, a1);
            a2 = fmaf(bf_lo(rv[j].y), nm, a2); a3 = fmaf(bf_hi(rv[j].y), nm, a3);
            a4 = fmaf(bf_lo(rv[j].z), nm, a4); a5 = fmaf(bf_hi(rv[j].z), nm, a5);
            a6 = fmaf(bf_lo(rv[j].w), nm, a6); a7 = fmaf(bf_hi(rv[j].w), nm, a7);
        }
    }
    if (p < end) {
        uint4 ev = *(const uint4*)(epay + p);
        unsigned int ee[4] = {ev.x, ev.y, ev.z, ev.w};
        uint4 rv[4];
        #pragma unroll
        for (int j = 0; j < 4; ++j)
            rv[j] = *(const uint4*)(hin + (size_t)(ee[j] & 0xffffu) * C_H + c8);
        #pragma unroll
        for (int j = 0; j < 4; ++j) {
            float nm = h_bits2f((unsigned short)(ee[j] >> 16));
            a0 = fmaf(bf_lo(rv[j].x), nm, a0); a1 = fmaf(bf_hi(rv[j].x), nm, a1);
            a2 = fmaf(bf_lo(rv[j].y), nm, a2); a3 = fmaf(bf_hi(rv[j].y), nm, a3);
            a4 = fmaf(bf_lo(rv[j].z), nm, a4); a5 = fmaf(bf_hi(rv[j].z), nm, a5);
            a6 = fmaf(bf_lo(rv[j].w), nm, a6); a7 = fmaf(bf_hi(rv[j].w), nm, a7);
        }
    }
    float4 ba = *(const float4*)(bias + c8);
    float4 bb = *(const float4*)(bias + c8 + 4);
    a0 = fmaxf(a0 + ba.x, 0.f); a1 = fmaxf(a1 + ba.y, 0.f);
    a2 = fmaxf(a2 + ba.z, 0.f); a3 = fmaxf(a3 + ba.w, 0.f);
    a4 = fmaxf(a4 + bb.x, 0.f); a5 = fmaxf(a5 + bb.y, 0.f);
    a6 = fmaxf(a6 + bb.z, 0.f); a7 = fmaxf(a7 + bb.w, 0.f);
    uint4 o;
    o.x = pack2(a0, a1); o.y = pack2(a2, a3);
    o.z = pack2(a4, a5); o.w = pack2(a6, a7);
    *(uint4*)(out + (size_t)node * C_H + c8) = o;
}

// ================= fused layer: gather(A·H) -> LDS tile -> MFMA chain =================
template <bool FINAL>
__global__ void __launch_bounds__(256) fused_layer_kernel(
        const int* __restrict__ rowptr,
        const unsigned int* __restrict__ epay,
        const float* __restrict__ dinv,
        const unsigned short* __restrict__ hin,
        const unsigned short* __restrict__ Wp,
        const float* __restrict__ bias,
        const unsigned short* __restrict__ Wd1p,
        const float* __restrict__ bd1,
        const unsigned short* __restrict__ Wd2p,
        const float* __restrict__ bd2,
        unsigned short* __restrict__ out_b,
        float* __restrict__ out_f) {
    __shared__ unsigned short sG[16 * TSTRIDE];
    const int t = threadIdx.x;

    // ---- phase A: gather agg row into LDS tile, 8 edges in flight ----
    {
        int nl = t >> 4, c8 = (t & 15) << 3;
        int node = blockIdx.x * 16 + nl;
        float di = dinv[node], dii = di * di;
        uint4 raw = *(const uint4*)(hin + (size_t)node * C_H + c8);
        float a0 = bf_lo(raw.x) * dii, a1 = bf_hi(raw.x) * dii;
        float a2 = bf_lo(raw.y) * dii, a3 = bf_hi(raw.y) * dii;
        float a4 = bf_lo(raw.z) * dii, a5 = bf_hi(raw.z) * dii;
        float a6 = bf_lo(raw.w) * dii, a7 = bf_hi(raw.w) * dii;
        int beg = rowptr[node], end = rowptr[node + 1];
        int p = beg;
        for (; p + 8 <= end; p += 8) {
            uint4 ev0 = *(const uint4*)(epay + p);
            uint4 ev1 = *(const uint4*)(epay + p + 4);
            unsigned int ee[8] = {ev0.x, ev0.y, ev0.z, ev0.w, ev1.x, ev1.y, ev1.z, ev1.w};
            uint4 rv[8];
            #pragma unroll
            for (int j = 0; j < 8; ++j)
                rv[j] = *(const uint4*)(hin + (size_t)(ee[j] & 0xffffu) * C_H + c8);
            #pragma unroll
            for (int j = 0; j < 8; ++j) {
                float nm = h_bits2f((unsigned short)(ee[j] >> 16));
                a0 = fmaf(bf_lo(rv[j].x), nm, a0); a1 = fmaf(bf_hi(rv[j].x), nm, a1);
                a2 = fmaf(bf_lo(rv[j].y), nm, a2); a3 = fmaf(bf_hi(rv[j].y), nm, a3);
                a4 = fmaf(bf_lo(rv[j].z), nm, a4); a5 = fmaf(bf_hi(rv[j].z), nm, a5);
                a6 = fmaf(bf_lo(rv[j].w), nm, a6); a7 = fmaf(bf_hi(rv[j].w), nm, a7);
            }
        }
        if (p < end) {
            uint4 ev = *(const uint4*)(epay + p);
            unsigned int ee[4] = {ev.x, ev.y, ev.z, ev.w};
            uint4 rv[4];
            #pragma unroll
            for (int j = 0; j < 4; ++j)
                rv[j] = *(const uint4*)(hin + (size_t)(ee[j] & 0xffffu) * C_H + c8);
            #pragma unroll
            for (int j = 0; j < 4; ++j) {
                float nm = h_bits2f((unsigned short)(ee[j] >> 16));
                a0 = fmaf(bf_lo(rv[j].x), nm, a0); a1 = fmaf(bf_hi(rv[j].x), nm, a1);
                a2 = fmaf(bf_lo(rv[j].y), nm, a2); a3 = fmaf(bf_hi(rv[j].y), nm, a3);
                a4 = fmaf(bf_lo(rv[j].z), nm, a4); a5 = fmaf(bf_hi(rv[j].z), nm, a5);
                a6 = fmaf(bf_lo(rv[j].w), nm, a6); a7 = fmaf(bf_hi(rv[j].w), nm, a7);
            }
        }
        uint4 o;
        o.x = pack2(a0, a1); o.y = pack2(a2, a3);
        o.z = pack2(a4, a5); o.w = pack2(a6, a7);
        *(uint4*)(sG + nl * TSTRIDE + c8) = o;
    }
    __syncthreads();

    const int lane = t & 63, wave = t >> 6, quad = lane >> 4, row = lane & 15;
    const int node = blockIdx.x * 16 + row;

    // ---- mm1: tile @ Wp (COUT=128), bias+relu ----
    f32x4 acc0 = (f32x4){0.f, 0.f, 0.f, 0.f};
    f32x4 acc1 = (f32x4){0.f, 0.f, 0.f, 0.f};
    const int nb0 = 2 * wave, nb1 = 2 * wave + 1;
    #pragma unroll
    for (int kb = 0; kb < 4; ++kb) {
        bf16x8 hf = *(const bf16x8*)(sG + row * TSTRIDE + kb * 32 + quad * 8);
        bf16x8 wf0 = *(const bf16x8*)(Wp + ((size_t)(kb * 8 + nb0) * 64 + lane) * 8);
        bf16x8 wf1 = *(const bf16x8*)(Wp + ((size_t)(kb * 8 + nb1) * 64 + lane) * 8);
        acc0 = __builtin_amdgcn_mfma_f32_16x16x32_bf16(wf0, hf, acc0, 0, 0, 0);
        acc1 = __builtin_amdgcn_mfma_f32_16x16x32_bf16(wf1, hf, acc1, 0, 0, 0);
    }
    float4 ba0 = *(const float4*)(bias + nb0 * 16 + quad * 4);
    float4 ba1 = *(const float4*)(bias + nb1 * 16 + quad * 4);
    float v00 = fmaxf(acc0[0] + ba0.x, 0.f), v01 = fmaxf(acc0[1] + ba0.y, 0.f);
    float v02 = fmaxf(acc0[2] + ba0.z, 0.f), v03 = fmaxf(acc0[3] + ba0.w, 0.f);
    float v10 = fmaxf(acc1[0] + ba1.x, 0.f), v11 = fmaxf(acc1[1] + ba1.y, 0.f);
    float v12 = fmaxf(acc1[2] + ba1.z, 0.f), v13 = fmaxf(acc1[3] + ba1.w, 0.f);

    if (!FINAL) {
        uint2 o0, o1;
        o0.x = pack2(v00, v01); o0.y = pack2(v02, v03);
        o1.x = pack2(v10, v11); o1.y = pack2(v12, v13);
        *(uint2*)(out_b + (size_t)node * C_H + nb0 * 16 + quad * 4) = o0;
        *(uint2*)(out_b + (size_t)node * C_H + nb1 * 16 + quad * 4) = o1;
        return;
    }

    // ---- FINAL: H3 -> tile -> Wd1 -> tile -> Wd2 -> sigmoid -> out_f ----
    __syncthreads();
    {
        uint2 o0, o1;
        o0.x = pack2(v00, v01); o0.y = pack2(v02, v03);
        o1.x = pack2(v10, v11); o1.y = pack2(v12, v13);
        *(uint2*)(sG + row * TSTRIDE + nb0 * 16 + quad * 4) = o0;
        *(uint2*)(sG + row * TSTRIDE + nb1 * 16 + quad * 4) = o1;
    }
    __syncthreads();

    acc0 = (f32x4){0.f, 0.f, 0.f, 0.f};
    acc1 = (f32x4){0.f, 0.f, 0.f, 0.f};
    #pragma unroll
    for (int kb = 0; kb < 4; ++kb) {
        bf16x8 hf = *(const bf16x8*)(sG + row * TSTRIDE + kb * 32 + quad * 8);
        bf16x8 wf0 = *(const bf16x8*)(Wd1p + ((size_t)(kb * 8 + nb0) * 64 + lane) * 8);
        bf16x8 wf1 = *(const bf16x8*)(Wd1p + ((size_t)(kb * 8 + nb1) * 64 + lane) * 8);
        acc0 = __builtin_amdgcn_mfma_f32_16x16x32_bf16(wf0, hf, acc0, 0, 0, 0);
        acc1 = __builtin_amdgcn_mfma_f32_16x16x32_bf16(wf1, hf, acc1, 0, 0, 0);
    }
    ba0 = *(const float4*)(bd1 + nb0 * 16 + quad * 4);
    ba1 = *(const float4*)(bd1 + nb1 * 16 + quad * 4);
    v00 = fmaxf(acc0[0] + ba0.x, 0.f); v01 = fmaxf(acc0[1] + ba0.y, 0.f);
    v02 = fmaxf(acc0[2] + ba0.z, 0.f); v03 = fmaxf(acc0[3] + ba0.w, 0.f);
    v10 = fmaxf(acc1[0] + ba1.x, 0.f); v11 = fmaxf(acc1[1] + ba1.y, 0.f);
    v12 = fmaxf(acc1[2] + ba1.z, 0.f); v13 = fmaxf(acc1[3] + ba1.w, 0.f);
    __syncthreads();
    {
        uint2 o0, o1;
        o0.x = pack2(v00, v01); o0.y = pack2(v02, v03);
        o1.x = pack2(v10, v11); o1.y = pack2(v12, v13);
        *(uint2*)(sG + row * TSTRIDE + nb0 * 16 + quad * 4) = o0;
        *(uint2*)(sG + row * TSTRIDE + nb1 * 16 + quad * 4) = o1;
    }
    __syncthreads();

    f32x4 acc = (f32x4){0.f, 0.f, 0.f, 0.f};
    #pragma unroll
    for (int kb = 0; kb < 4; ++kb) {
        bf16x8 hf = *(const bf16x8*)(sG + row * TSTRIDE + kb * 32 + quad * 8);
        bf16x8 wf = *(const bf16x8*)(Wd2p + ((size_t)(kb * 4 + wave) * 64 + lane) * 8);
        acc = __builtin_amdgcn_mfma_f32_16x16x32_bf16(wf, hf, acc, 0, 0, 0);
    }
    int ch = wave * 16 + quad * 4;
    float4 b4 = *(const float4*)(bd2 + ch);
    float4 r;
    r.x = 1.f / (1.f + expf(-(acc[0] + b4.x)));
    r.y = 1.f / (1.f + expf(-(acc[1] + b4.y)));
    r.z = 1.f / (1.f + expf(-(acc[2] + b4.z)));
    r.w = 1.f / (1.f + expf(-(acc[3] + b4.w)));
    *(float4*)(out_f + (size_t)node * C_OUT + ch) = r;
}

extern "C" void kernel_launch(void* const* d_in, const int* in_sizes, int n_in,
                              void* d_out, int out_size, void* d_ws, size_t ws_size,
                              hipStream_t stream) {
    const float* x   = (const float*)d_in[0];
    const int*   ei  = (const int*)d_in[1];
    const float* W1  = (const float*)d_in[2];
    const float* b1  = (const float*)d_in[3];
    const float* W2  = (const float*)d_in[4];
    const float* b2  = (const float*)d_in[5];
    const float* W3  = (const float*)d_in[6];
    const float* b3  = (const float*)d_in[7];
    const float* Wd1 = (const float*)d_in[8];
    const float* bd1 = (const float*)d_in[9];
    const float* Wd2 = (const float*)d_in[10];
    const float* bd2 = (const float*)d_in[11];

    const int* src = ei;
    const int* dst = ei + N_EDGES;

    char* base = (char*)d_ws;
    size_t off = 0;
    auto alloc = [&](size_t bytes) { char* p = base + off; off += (bytes + 255) & ~size_t(255); return p; };
    int*            counts2 = (int*)alloc((size_t)N_NODES * 8 * 4);   // (dst, src-tile) hist -> bucket offsets
    unsigned int*   epay   = (unsigned int*)alloc((size_t)E_PAD * 4);
    int*            rank   = (int*)alloc((size_t)N_EDGES * 4);
    float*          dinv   = (float*)alloc(N_NODES * 4);
    int*            rowptr = (int*)alloc((N_NODES + 1) * 4);
    int*            eblk   = (int*)alloc(N_NODES * 4);
    int*            bsum   = (int*)alloc(256 * 4);
    unsigned short* XW1    = (unsigned short*)alloc((size_t)N_NODES * C_H * 2);
    unsigned short* bufA   = (unsigned short*)alloc((size_t)N_NODES * C_H * 2);
    unsigned short* bufB   = (unsigned short*)alloc((size_t)N_NODES * C_H * 2);
    unsigned short* P1     = (unsigned short*)alloc(128 * 128 * 2);
    unsigned short* P2     = (unsigned short*)alloc(128 * 128 * 2);
    unsigned short* P3     = (unsigned short*)alloc(128 * 128 * 2);
    unsigned short* Pd1    = (unsigned short*)alloc(128 * 128 * 2);
    unsigned short* Pd2    = (unsigned short*)alloc(128 * 64 * 2);

    const int T = 256;
    dim3 blk(T);
    dim3 gN((N_NODES + T - 1) / T);            // 196
    dim3 gPrep(3125 + 288 + 928);              // hist + pack + zero
    dim3 gFillMM(MM_BLKS + 3125);              // mm + fill
    dim3 gFused(N_NODES / 16);                 // 3125, exact

    hipMemsetAsync(counts2, 0, (size_t)N_NODES * 8 * 4, stream);
    prep_kernel<<<gPrep, blk, 0, stream>>>(src, dst, counts2, rank,
                                           W1, W2, W3, Wd1, Wd2,
                                           P1, P2, P3, Pd1, Pd2, epay);
    scan1_kernel<<<gN, blk, 0, stream>>>(counts2, eblk, bsum, dinv);
    scanB_kernel<<<gN, blk, 0, stream>>>(eblk, bsum, rowptr);
    fill_mm_kernel<<<gFillMM, blk, 0, stream>>>(x, P1, XW1, src, dst, dinv,
                                                rowptr, counts2, rank, epay);

    // ---- layer 1: relu(agg(XW1) + b1) -> bufA (pure gather, tile-ordered edges) ----
    gather1_kernel<<<gFused, blk, 0, stream>>>(rowptr, epay, dinv, XW1, b1, bufA);
    // ---- layer 2 ----
    fused_layer_kernel<false><<<gFused, blk, 0, stream>>>(
        rowptr, epay, dinv, bufA, P2, b2, nullptr, nullptr, nullptr, nullptr, bufB, nullptr);
    // ---- layer 3 + dense head ----
    fused_layer_kernel<true><<<gFused, blk, 0, stream>>>(
        rowptr, epay, dinv, bufB, P3, b3, Pd1, bd1, Pd2, bd2, nullptr, (float*)d_out);
}